// Round 5
// baseline (268.988 us; speedup 1.0000x reference)
//
#include <hip/hip_runtime.h>
#include <math.h>

// Problem constants
#define NB   2048     // batch
#define ND   1024     // dim
#define INV_TEMP 10.0f
#define LAMBDA_CS 0.5f

using short8  = __attribute__((ext_vector_type(8))) short;
using floatx4 = __attribute__((ext_vector_type(4))) float;

__device__ __forceinline__ ushort f32_to_bf16_rne(float f) {
  union { float f; unsigned u; } v; v.f = f;
  unsigned u = v.u;
  u += 0x7FFFu + ((u >> 16) & 1u);   // round-to-nearest-even
  return (ushort)(u >> 16);
}

// ---------------------------------------------------------------------------
// Kernel 1: fused row L2-normalize (-> bf16 M, t-order {e,k,et,kt}) + cs-reg
// partial per row + rowsum/counter zero-init. One block per row b.
// ---------------------------------------------------------------------------
__global__ __launch_bounds__(256) void k_norm_reg(
    const float* __restrict__ e, const float* __restrict__ k,
    const float* __restrict__ et, const float* __restrict__ kt,
    const float* __restrict__ ratios,
    ushort* __restrict__ M, float* __restrict__ reg_partial,
    float* __restrict__ rowsum, int* __restrict__ counter)
{
  const int b = blockIdx.x, tid = threadIdx.x;
  const int wave = tid >> 6, lane = tid & 63;

  float4 ve  = ((const float4*)(e  + (size_t)b * ND))[tid];
  float4 vk  = ((const float4*)(k  + (size_t)b * ND))[tid];
  float4 vet = ((const float4*)(et + (size_t)b * ND))[tid];
  float4 vkt = ((const float4*)(kt + (size_t)b * ND))[tid];

  float s0 = ve.x*ve.x + ve.y*ve.y + ve.z*ve.z + ve.w*ve.w;
  float s1 = vk.x*vk.x + vk.y*vk.y + vk.z*vk.z + vk.w*vk.w;
  float s2 = vet.x*vet.x + vet.y*vet.y + vet.z*vet.z + vet.w*vet.w;
  float s3 = vkt.x*vkt.x + vkt.y*vkt.y + vkt.z*vkt.z + vkt.w*vkt.w;
  #pragma unroll
  for (int o = 1; o < 64; o <<= 1) {
    s0 += __shfl_xor(s0, o); s1 += __shfl_xor(s1, o);
    s2 += __shfl_xor(s2, o); s3 += __shfl_xor(s3, o);
  }
  __shared__ float red[4][4];
  if (lane == 0) { red[wave][0] = s0; red[wave][1] = s1; red[wave][2] = s2; red[wave][3] = s3; }
  __syncthreads();
  const float ie  = 1.0f / sqrtf(red[0][0] + red[1][0] + red[2][0] + red[3][0]);
  const float ik  = 1.0f / sqrtf(red[0][1] + red[1][1] + red[2][1] + red[3][1]);
  const float iet = 1.0f / sqrtf(red[0][2] + red[1][2] + red[2][2] + red[3][2]);
  const float ikt = 1.0f / sqrtf(red[0][3] + red[1][3] + red[2][3] + red[3][3]);

  // write normalized bf16 rows, t order {0:e, 1:k, 2:et, 3:kt}
  {
    ushort o4[4];
    o4[0] = f32_to_bf16_rne(ve.x * ie);  o4[1] = f32_to_bf16_rne(ve.y * ie);
    o4[2] = f32_to_bf16_rne(ve.z * ie);  o4[3] = f32_to_bf16_rne(ve.w * ie);
    *(ushort4*)(M + ((size_t)0 * NB + b) * ND + tid * 4) = *(ushort4*)o4;
    o4[0] = f32_to_bf16_rne(vk.x * ik);  o4[1] = f32_to_bf16_rne(vk.y * ik);
    o4[2] = f32_to_bf16_rne(vk.z * ik);  o4[3] = f32_to_bf16_rne(vk.w * ik);
    *(ushort4*)(M + ((size_t)1 * NB + b) * ND + tid * 4) = *(ushort4*)o4;
    o4[0] = f32_to_bf16_rne(vet.x * iet); o4[1] = f32_to_bf16_rne(vet.y * iet);
    o4[2] = f32_to_bf16_rne(vet.z * iet); o4[3] = f32_to_bf16_rne(vet.w * iet);
    *(ushort4*)(M + ((size_t)2 * NB + b) * ND + tid * 4) = *(ushort4*)o4;
    o4[0] = f32_to_bf16_rne(vkt.x * ikt); o4[1] = f32_to_bf16_rne(vkt.y * ikt);
    o4[2] = f32_to_bf16_rne(vkt.z * ikt); o4[3] = f32_to_bf16_rne(vkt.w * ikt);
    *(ushort4*)(M + ((size_t)3 * NB + b) * ND + tid * 4) = *(ushort4*)o4;
  }

  // cs-reg partial
  const float r = ratios[b], rm = 1.0f - r;
  float a1 = 0.f, a2 = 0.f;
  {
    float en, kn, d1, d2;
    en = ve.x*ie; kn = vk.x*ik;
    d1 = vet.x*iet - (r*en + rm*kn); d2 = vkt.x*ikt - (rm*en + r*kn);
    a1 += d1*d1; a2 += d2*d2;
    en = ve.y*ie; kn = vk.y*ik;
    d1 = vet.y*iet - (r*en + rm*kn); d2 = vkt.y*ikt - (rm*en + r*kn);
    a1 += d1*d1; a2 += d2*d2;
    en = ve.z*ie; kn = vk.z*ik;
    d1 = vet.z*iet - (r*en + rm*kn); d2 = vkt.z*ikt - (rm*en + r*kn);
    a1 += d1*d1; a2 += d2*d2;
    en = ve.w*ie; kn = vk.w*ik;
    d1 = vet.w*iet - (r*en + rm*kn); d2 = vkt.w*ikt - (rm*en + r*kn);
    a1 += d1*d1; a2 += d2*d2;
  }
  #pragma unroll
  for (int o = 1; o < 64; o <<= 1) { a1 += __shfl_xor(a1, o); a2 += __shfl_xor(a2, o); }
  __shared__ float red2[4][2];
  if (lane == 0) { red2[wave][0] = a1; red2[wave][1] = a2; }
  __syncthreads();
  if (tid == 0) {
    float t1 = red2[0][0] + red2[1][0] + red2[2][0] + red2[3][0];
    float t2 = red2[0][1] + red2[1][1] + red2[2][1] + red2[3][1];
    reg_partial[b] = sqrtf(t1) + sqrtf(t2);
    rowsum[b] = 0.f;            // zero-init for gemm's atomics
    rowsum[NB + b] = 0.f;
    if (b == 0) counter[0] = 0;
  }
}

// ---------------------------------------------------------------------------
// Kernel 2: 128x128-tile, BK=32, 4-wave, 3-LDS-buffer counted-vmcnt GEMM
// (R3's pipeline MINUS the schedule poison: no sched_barrier(0), no inline
// lgkmcnt, no setprio -- ds_read->MFMA ordering is pure dataflow, left to
// the compiler) + fused exp + atomic row-sum + diagonal capture (atomicExch,
// device-coherent) + symmetric col-sum mirror + last-block final reduction.
//   In-flight discipline (T4): per wave, 8 gload_lds (tiles t+1, t+2) stay
//   outstanding across barriers; vmcnt(4) per step retires only tile t+1's.
//   This ~2-3x the in-flight staging bytes vs the single-buffered R0 loop,
//   which Little's law says is the current throughput limiter.
//   Grid: 1552 = 1024 (right half) + 528 (upper-tri incl diagonal).
//   LDS 50 KB -> 3 blocks/CU (also AGPR+VGPR ~132 -> 3 waves/SIMD).
// ---------------------------------------------------------------------------

#define GLDS(GP, LP)                                                           \
  __builtin_amdgcn_global_load_lds(                                            \
      (const __attribute__((address_space(1))) unsigned int*)(GP),             \
      (__attribute__((address_space(3))) unsigned int*)(LP), 16, 0, 0)

// stage tile TT (K-offset TT*32) into buffer BUF; 4 gloads per wave
#define STAGE(TT, BUF) do {                                                    \
  GLDS(gA + (size_t)(c0 * 16 + srow) * ND + (TT) * 32 + scol * 8,              \
       &As[BUF][c0 * 512]);                                                    \
  GLDS(gA + (size_t)(c1 * 16 + srow) * ND + (TT) * 32 + scol * 8,              \
       &As[BUF][c1 * 512]);                                                    \
  GLDS(gB + (size_t)(c0 * 16 + srow) * ND + (TT) * 32 + scol * 8,              \
       &Bs[BUF][c0 * 512]);                                                    \
  GLDS(gB + (size_t)(c1 * 16 + srow) * ND + (TT) * 32 + scol * 8,              \
       &Bs[BUF][c1 * 512]);                                                    \
} while (0)

__global__ __launch_bounds__(256) void k_gemm_exp_rowsum(
    const ushort* __restrict__ M,
    float* __restrict__ rowsum,   // [4096] atomic accumulators
    float* __restrict__ diag,     // [2][4][2048] (side, t, n); slot 4 unused
    const float* __restrict__ reg_partial,
    int* __restrict__ counter,
    float* __restrict__ out)
{
  __shared__ __align__(16) ushort As[3][4096];   // 3 x 8KB
  __shared__ __align__(16) ushort Bs[3][4096];   // 3 x 8KB
  __shared__ float redR[256];
  __shared__ float redC[256];
  __shared__ int lastFlag;

  // decode (bx, by) from linear block id
  int bx, by;
  {
    int idx = blockIdx.x;
    if (idx < 1024) { by = idx >> 5; bx = 32 + (idx & 31); }
    else {
      int t = idx - 1024; by = 0;
      while (t >= 32 - by) { t -= 32 - by; ++by; }
      bx = by + t;
    }
  }
  const bool sym = (bx < 32) && (bx > by);
  const int j0 = bx * 128;
  const int i0 = by * 128;

  const int tid  = threadIdx.x;
  const int wave = tid >> 6;
  const int lane = tid & 63;
  const int q = lane >> 4;       // quad 0..3
  const int m = lane & 15;       // spatial index within 16
  const int wrow = (wave >> 1) * 64;
  const int wcol = (wave & 1) * 64;

  floatx4 acc[4][4] = {};

  // staging geometry: chunk = 16 rows x 32 K-cols (1 KB); XOR col swizzle
  const int srow = lane >> 2;
  const int scol = (lane & 3) ^ ((srow >> 1) & 3);
  const int c0 = wave * 2, c1 = c0 + 1;

  const ushort* gA = M + (size_t)i0 * ND;
  const ushort* gB = M + (size_t)j0 * ND;

  int aoff[4], boff[4];
  #pragma unroll
  for (int x = 0; x < 4; ++x) {
    const int sw = (q ^ ((m >> 1) & 3)) * 8;
    aoff[x] = (wrow + x * 16 + m) * 32 + sw;
    boff[x] = (wcol + x * 16 + m) * 32 + sw;
  }

  // prologue: tiles 0 and 1; retire tile0's 4 loads (tile1's stay in flight)
  STAGE(0, 0);
  STAGE(1, 1);
  asm volatile("s_waitcnt vmcnt(4)" ::: "memory");
  __builtin_amdgcn_s_barrier();

  int bcur = 0, bnext = 1, bstage = 2;
  #pragma unroll 1
  for (int t = 0; t < 32; ++t) {
    // stage tile t+2 into the buffer last read at t-1 (all waves past that
    // barrier). Wrap at the tail is a harmless refetch, drained below.
    STAGE((t + 2) & 31, bstage);

    // compute tile t: ds_read -> MFMA is pure dataflow; the compiler
    // schedules lgkmcnt fine-grained (m97 evidence). No asm in this path.
    short8 af[4], bf[4];
    #pragma unroll
    for (int x = 0; x < 4; ++x) {
      af[x] = *(const short8*)&As[bcur][aoff[x]];
      bf[x] = *(const short8*)&Bs[bcur][boff[x]];
    }
    #pragma unroll
    for (int mi = 0; mi < 4; ++mi)
      #pragma unroll
      for (int ni = 0; ni < 4; ++ni)
        acc[mi][ni] = __builtin_amdgcn_mfma_f32_16x16x32_bf16(
            af[mi], bf[ni], acc[mi][ni], 0, 0, 0);

    // retire tile t+1's 4 loads; keep tile t+2's 4 in flight (never 0)
    asm volatile("s_waitcnt vmcnt(4)" ::: "memory");
    __builtin_amdgcn_s_barrier();

    const int tmp = bcur; bcur = bnext; bnext = bstage; bstage = tmp;
  }

  __syncthreads();   // full drain (incl. wrap-around stages) before epilogue

  // Epilogue. C/D layout: col = lane&15, row = q*4 + reg  [m89/m91]
  float colAcc[4] = {0.f, 0.f, 0.f, 0.f};
  #pragma unroll
  for (int mi = 0; mi < 4; ++mi) {
    #pragma unroll
    for (int r = 0; r < 4; ++r) {
      const int ig = i0 + wrow + mi * 16 + q * 4 + r;
      float s = 0.f;
      #pragma unroll
      for (int ni = 0; ni < 4; ++ni) {
        const float v = __expf(acc[mi][ni][r] * INV_TEMP);
        s += v;
        colAcc[ni] += v;
        const int jg = j0 + wcol + ni * 16 + m;
        if (((ig ^ jg) & (NB - 1)) == 0) {
          // atomicExch: device-coherent store (read later by the last block)
          atomicExch(&diag[(((ig >> 11) << 2) + (jg >> 11)) * NB + (ig & (NB - 1))], v);
        }
      }
      s += __shfl_xor(s, 1);
      s += __shfl_xor(s, 2);
      s += __shfl_xor(s, 4);
      s += __shfl_xor(s, 8);
      if (m == 0) redR[(wave & 1) * 128 + wrow + mi * 16 + q * 4 + r] = s;
    }
  }
  #pragma unroll
  for (int ni = 0; ni < 4; ++ni) {
    float c = colAcc[ni];
    c += __shfl_xor(c, 16);
    c += __shfl_xor(c, 32);
    if (q == 0) redC[(wave >> 1) * 128 + wcol + ni * 16 + m] = c;
  }
  __syncthreads();
  if (tid < 128) {
    atomicAdd(&rowsum[i0 + tid], redR[tid] + redR[128 + tid]);
    if (sym)
      atomicAdd(&rowsum[j0 + tid], redC[tid] + redC[128 + tid]);
  }

  // ---- last-block-done final reduction (replaces k_final kernel) ----
  __threadfence();   // release: rowsum/diag visible before counter bump
  if (tid == 0) {
    const int old = atomicAdd(counter, 1);
    lastFlag = (old == (int)gridDim.x - 1);
  }
  __syncthreads();
  if (!lastFlag) return;
  __threadfence();   // acquire: invalidate stale cached rowsum/diag

  float l = 0.f, g = 0.f;
  #pragma unroll
  for (int i = 0; i < 8; ++i) {
    const int n = tid + i * 256;   // 0..2047
    const float se = rowsum[n];
    const float sk = rowsum[NB + n];
    const float d_ee  = diag[0 * NB + n];
    const float d_ek  = diag[1 * NB + n];
    const float d_eet = diag[2 * NB + n];
    const float d_ekt = diag[3 * NB + n];
    const float d_kk  = diag[5 * NB + n];
    const float d_ket = diag[6 * NB + n];
    const float d_kkt = diag[7 * NB + n];
    const float num_e = d_ek + d_eet + d_ekt;
    const float num_k = d_ek + d_ket + d_kkt;   // k.e diag == e.k diag (mirror)
    l += logf((se - d_ee) / num_e) + logf((sk - d_kk) / num_k);
    g += reg_partial[n];
  }
  #pragma unroll
  for (int o = 1; o < 64; o <<= 1) { l += __shfl_xor(l, o); g += __shfl_xor(g, o); }
  if (lane == 0) { redR[wave] = l; redR[8 + wave] = g; }
  __syncthreads();
  if (tid == 0) {
    const float L = redR[0] + redR[1] + redR[2] + redR[3];
    const float G = redR[8] + redR[9] + redR[10] + redR[11];
    const float contrastive = L * (1.0f / (2.0f * NB));
    const float cs = G * (1.0f / NB);
    out[0] = contrastive + LAMBDA_CS * cs;
    out[1] = contrastive;
    out[2] = cs;
  }
}

// ---------------------------------------------------------------------------
extern "C" void kernel_launch(void* const* d_in, const int* in_sizes, int n_in,
                              void* d_out, int out_size, void* d_ws, size_t ws_size,
                              hipStream_t stream) {
  const float* english = (const float*)d_in[0];
  const float* etok    = (const float*)d_in[1];
  const float* ktoe    = (const float*)d_in[2];
  const float* korean  = (const float*)d_in[3];
  const float* ratios  = (const float*)d_in[4];

  char* ws = (char*)d_ws;
  const size_t OFF_M    = 0;                                   // 16777216 B
  const size_t OFF_ROW  = OFF_M + (size_t)8192 * 1024 * 2;     // 4096*4
  const size_t OFF_DIAG = OFF_ROW + (size_t)4096 * 4;          // 8*2048*4
  const size_t OFF_REG  = OFF_DIAG + 8 * NB * sizeof(float);   // 2048*4
  const size_t OFF_CNT  = OFF_REG + NB * sizeof(float);        // 4

  ushort* M           = (ushort*)(ws + OFF_M);
  float* rowsum       = (float*)(ws + OFF_ROW);
  float* diag         = (float*)(ws + OFF_DIAG);
  float* reg_partial  = (float*)(ws + OFF_REG);
  int*   counter      = (int*)(ws + OFF_CNT);

  k_norm_reg<<<dim3(NB), 256, 0, stream>>>(english, korean, etok, ktoe, ratios,
                                           M, reg_partial, rowsum, counter);
  k_gemm_exp_rowsum<<<dim3(1552), 256, 0, stream>>>(M, rowsum, diag,
                                                    reg_partial, counter,
                                                    (float*)d_out);
}

// Round 6
// 249.438 us; speedup vs baseline: 1.0784x; 1.0784x over previous
//
#include <hip/hip_runtime.h>
#include <math.h>

// Problem constants
#define NB   2048     // batch
#define ND   1024     // dim
#define INV_TEMP 10.0f
#define LAMBDA_CS 0.5f

using short8  = __attribute__((ext_vector_type(8))) short;
using floatx4 = __attribute__((ext_vector_type(4))) float;

__device__ __forceinline__ ushort f32_to_bf16_rne(float f) {
  union { float f; unsigned u; } v; v.f = f;
  unsigned u = v.u;
  u += 0x7FFFu + ((u >> 16) & 1u);   // round-to-nearest-even
  return (ushort)(u >> 16);
}

// ---------------------------------------------------------------------------
// Kernel 1: fused row L2-normalize (-> bf16 M, t-order {e,k,et,kt}) + cs-reg
// partial per row + rowsum/counter zero-init. One block per row b.
// ---------------------------------------------------------------------------
__global__ __launch_bounds__(256) void k_norm_reg(
    const float* __restrict__ e, const float* __restrict__ k,
    const float* __restrict__ et, const float* __restrict__ kt,
    const float* __restrict__ ratios,
    ushort* __restrict__ M, float* __restrict__ reg_partial,
    float* __restrict__ rowsum, int* __restrict__ counter)
{
  const int b = blockIdx.x, tid = threadIdx.x;
  const int wave = tid >> 6, lane = tid & 63;

  float4 ve  = ((const float4*)(e  + (size_t)b * ND))[tid];
  float4 vk  = ((const float4*)(k  + (size_t)b * ND))[tid];
  float4 vet = ((const float4*)(et + (size_t)b * ND))[tid];
  float4 vkt = ((const float4*)(kt + (size_t)b * ND))[tid];

  float s0 = ve.x*ve.x + ve.y*ve.y + ve.z*ve.z + ve.w*ve.w;
  float s1 = vk.x*vk.x + vk.y*vk.y + vk.z*vk.z + vk.w*vk.w;
  float s2 = vet.x*vet.x + vet.y*vet.y + vet.z*vet.z + vet.w*vet.w;
  float s3 = vkt.x*vkt.x + vkt.y*vkt.y + vkt.z*vkt.z + vkt.w*vkt.w;
  #pragma unroll
  for (int o = 1; o < 64; o <<= 1) {
    s0 += __shfl_xor(s0, o); s1 += __shfl_xor(s1, o);
    s2 += __shfl_xor(s2, o); s3 += __shfl_xor(s3, o);
  }
  __shared__ float red[4][4];
  if (lane == 0) { red[wave][0] = s0; red[wave][1] = s1; red[wave][2] = s2; red[wave][3] = s3; }
  __syncthreads();
  const float ie  = 1.0f / sqrtf(red[0][0] + red[1][0] + red[2][0] + red[3][0]);
  const float ik  = 1.0f / sqrtf(red[0][1] + red[1][1] + red[2][1] + red[3][1]);
  const float iet = 1.0f / sqrtf(red[0][2] + red[1][2] + red[2][2] + red[3][2]);
  const float ikt = 1.0f / sqrtf(red[0][3] + red[1][3] + red[2][3] + red[3][3]);

  // write normalized bf16 rows, t order {0:e, 1:k, 2:et, 3:kt}
  {
    ushort o4[4];
    o4[0] = f32_to_bf16_rne(ve.x * ie);  o4[1] = f32_to_bf16_rne(ve.y * ie);
    o4[2] = f32_to_bf16_rne(ve.z * ie);  o4[3] = f32_to_bf16_rne(ve.w * ie);
    *(ushort4*)(M + ((size_t)0 * NB + b) * ND + tid * 4) = *(ushort4*)o4;
    o4[0] = f32_to_bf16_rne(vk.x * ik);  o4[1] = f32_to_bf16_rne(vk.y * ik);
    o4[2] = f32_to_bf16_rne(vk.z * ik);  o4[3] = f32_to_bf16_rne(vk.w * ik);
    *(ushort4*)(M + ((size_t)1 * NB + b) * ND + tid * 4) = *(ushort4*)o4;
    o4[0] = f32_to_bf16_rne(vet.x * iet); o4[1] = f32_to_bf16_rne(vet.y * iet);
    o4[2] = f32_to_bf16_rne(vet.z * iet); o4[3] = f32_to_bf16_rne(vet.w * iet);
    *(ushort4*)(M + ((size_t)2 * NB + b) * ND + tid * 4) = *(ushort4*)o4;
    o4[0] = f32_to_bf16_rne(vkt.x * ikt); o4[1] = f32_to_bf16_rne(vkt.y * ikt);
    o4[2] = f32_to_bf16_rne(vkt.z * ikt); o4[3] = f32_to_bf16_rne(vkt.w * ikt);
    *(ushort4*)(M + ((size_t)3 * NB + b) * ND + tid * 4) = *(ushort4*)o4;
  }

  // cs-reg partial
  const float r = ratios[b], rm = 1.0f - r;
  float a1 = 0.f, a2 = 0.f;
  {
    float en, kn, d1, d2;
    en = ve.x*ie; kn = vk.x*ik;
    d1 = vet.x*iet - (r*en + rm*kn); d2 = vkt.x*ikt - (rm*en + r*kn);
    a1 += d1*d1; a2 += d2*d2;
    en = ve.y*ie; kn = vk.y*ik;
    d1 = vet.y*iet - (r*en + rm*kn); d2 = vkt.y*ikt - (rm*en + r*kn);
    a1 += d1*d1; a2 += d2*d2;
    en = ve.z*ie; kn = vk.z*ik;
    d1 = vet.z*iet - (r*en + rm*kn); d2 = vkt.z*ikt - (rm*en + r*kn);
    a1 += d1*d1; a2 += d2*d2;
    en = ve.w*ie; kn = vk.w*ik;
    d1 = vet.w*iet - (r*en + rm*kn); d2 = vkt.w*ikt - (rm*en + r*kn);
    a1 += d1*d1; a2 += d2*d2;
  }
  #pragma unroll
  for (int o = 1; o < 64; o <<= 1) { a1 += __shfl_xor(a1, o); a2 += __shfl_xor(a2, o); }
  __shared__ float red2[4][2];
  if (lane == 0) { red2[wave][0] = a1; red2[wave][1] = a2; }
  __syncthreads();
  if (tid == 0) {
    float t1 = red2[0][0] + red2[1][0] + red2[2][0] + red2[3][0];
    float t2 = red2[0][1] + red2[1][1] + red2[2][1] + red2[3][1];
    reg_partial[b] = sqrtf(t1) + sqrtf(t2);
    rowsum[b] = 0.f;            // zero-init for gemm's atomics
    rowsum[NB + b] = 0.f;
    if (b == 0) counter[0] = 0;
  }
}

// ---------------------------------------------------------------------------
// Kernel 2: EXACT R0 gemm structure (single-buffered 128x128 tile, BK=32,
// two __syncthreads per K-step, compiler-scheduled waits -- proven 83 us,
// MfmaUtil 25%, 0 bank conflicts) + fused exp + atomic row-sum + diagonal
// capture (atomicExch, device-coherent) + symmetric col-sum mirror +
// last-block final reduction (proven in R5; saves a ~20 us launch).
//   Grid: 1552 = 1024 (right half, bx in [32,64)) + 528 (upper-tri incl
//   diagonal of left half, bx in [by,32)).
//   NOTE: counted-vmcnt pipelining attempts (R1/R3/R5) all regressed --
//   the compiler inserts vmcnt(0) before ds_reads of gload_lds-written LDS;
//   do not re-attempt at HIP source level.
// ---------------------------------------------------------------------------
__global__ __launch_bounds__(256) void k_gemm_exp_rowsum(
    const ushort* __restrict__ M,
    float* __restrict__ rowsum,   // [4096] atomic accumulators
    float* __restrict__ diag,     // [2][4][2048] (side, t, n); slot 4 unused
    const float* __restrict__ reg_partial,
    int* __restrict__ counter,
    float* __restrict__ out)
{
  __shared__ ushort As[128 * 32];
  __shared__ ushort Bs[128 * 32];
  __shared__ float redR[256];
  __shared__ float redC[256];
  __shared__ int lastFlag;

  // decode (bx, by) from linear block id
  int bx, by;
  {
    int idx = blockIdx.x;
    if (idx < 1024) { by = idx >> 5; bx = 32 + (idx & 31); }
    else {
      int t = idx - 1024; by = 0;
      while (t >= 32 - by) { t -= 32 - by; ++by; }
      bx = by + t;
    }
  }
  const bool sym = (bx < 32) && (bx > by);
  const int j0 = bx * 128;
  const int i0 = by * 128;

  const int tid  = threadIdx.x;
  const int wave = tid >> 6;
  const int lane = tid & 63;
  const int q = lane >> 4;       // quad 0..3
  const int m = lane & 15;       // spatial index within 16
  const int wrow = (wave >> 1) * 64;
  const int wcol = (wave & 1) * 64;

  floatx4 acc[4][4] = {};

  // staging: chunk = 16 rows x 64B; XOR swizzle so ds_read_b128 is 2-way only
  const int srow = lane >> 2;
  const int scol = (lane & 3) ^ ((srow >> 1) & 3);
  const int c0 = wave * 2, c1 = c0 + 1;

  const ushort* gA = M + (size_t)i0 * ND;
  const ushort* gB = M + (size_t)j0 * ND;

  int aoff[4], boff[4];
  #pragma unroll
  for (int x = 0; x < 4; ++x) {
    const int sw = (q ^ ((m >> 1) & 3)) * 8;
    aoff[x] = (wrow + x * 16 + m) * 32 + sw;
    boff[x] = (wcol + x * 16 + m) * 32 + sw;
  }

  for (int k0 = 0; k0 < ND; k0 += 32) {
    __syncthreads();
    {
      const ushort* g = gA + (size_t)(c0 * 16 + srow) * ND + k0 + scol * 8;
      __builtin_amdgcn_global_load_lds(
          (const __attribute__((address_space(1))) unsigned int*)g,
          (__attribute__((address_space(3))) unsigned int*)&As[c0 * 512], 16, 0, 0);
    }
    {
      const ushort* g = gA + (size_t)(c1 * 16 + srow) * ND + k0 + scol * 8;
      __builtin_amdgcn_global_load_lds(
          (const __attribute__((address_space(1))) unsigned int*)g,
          (__attribute__((address_space(3))) unsigned int*)&As[c1 * 512], 16, 0, 0);
    }
    {
      const ushort* g = gB + (size_t)(c0 * 16 + srow) * ND + k0 + scol * 8;
      __builtin_amdgcn_global_load_lds(
          (const __attribute__((address_space(1))) unsigned int*)g,
          (__attribute__((address_space(3))) unsigned int*)&Bs[c0 * 512], 16, 0, 0);
    }
    {
      const ushort* g = gB + (size_t)(c1 * 16 + srow) * ND + k0 + scol * 8;
      __builtin_amdgcn_global_load_lds(
          (const __attribute__((address_space(1))) unsigned int*)g,
          (__attribute__((address_space(3))) unsigned int*)&Bs[c1 * 512], 16, 0, 0);
    }
    __syncthreads();

    short8 af[4], bf[4];
    #pragma unroll
    for (int x = 0; x < 4; ++x) {
      af[x] = *(const short8*)&As[aoff[x]];
      bf[x] = *(const short8*)&Bs[boff[x]];
    }
    #pragma unroll
    for (int mi = 0; mi < 4; ++mi)
      #pragma unroll
      for (int ni = 0; ni < 4; ++ni)
        acc[mi][ni] = __builtin_amdgcn_mfma_f32_16x16x32_bf16(
            af[mi], bf[ni], acc[mi][ni], 0, 0, 0);
  }

  // Epilogue. C/D layout: col = lane&15, row = q*4 + reg  [m89/m91]
  float colAcc[4] = {0.f, 0.f, 0.f, 0.f};
  #pragma unroll
  for (int mi = 0; mi < 4; ++mi) {
    #pragma unroll
    for (int r = 0; r < 4; ++r) {
      const int ig = i0 + wrow + mi * 16 + q * 4 + r;
      float s = 0.f;
      #pragma unroll
      for (int ni = 0; ni < 4; ++ni) {
        const float v = __expf(acc[mi][ni][r] * INV_TEMP);
        s += v;
        colAcc[ni] += v;
        const int jg = j0 + wcol + ni * 16 + m;
        if (((ig ^ jg) & (NB - 1)) == 0) {
          // atomicExch: device-coherent store (read later by the last block)
          atomicExch(&diag[(((ig >> 11) << 2) + (jg >> 11)) * NB + (ig & (NB - 1))], v);
        }
      }
      s += __shfl_xor(s, 1);
      s += __shfl_xor(s, 2);
      s += __shfl_xor(s, 4);
      s += __shfl_xor(s, 8);
      if (m == 0) redR[(wave & 1) * 128 + wrow + mi * 16 + q * 4 + r] = s;
    }
  }
  #pragma unroll
  for (int ni = 0; ni < 4; ++ni) {
    float c = colAcc[ni];
    c += __shfl_xor(c, 16);
    c += __shfl_xor(c, 32);
    if (q == 0) redC[(wave >> 1) * 128 + wcol + ni * 16 + m] = c;
  }
  __syncthreads();
  if (tid < 128) {
    atomicAdd(&rowsum[i0 + tid], redR[tid] + redR[128 + tid]);
    if (sym)
      atomicAdd(&rowsum[j0 + tid], redC[tid] + redC[128 + tid]);
  }

  // ---- last-block-done final reduction (replaces k_final kernel) ----
  __threadfence();   // release: rowsum/diag visible before counter bump
  if (tid == 0) {
    const int old = atomicAdd(counter, 1);
    lastFlag = (old == (int)gridDim.x - 1);
  }
  __syncthreads();
  if (!lastFlag) return;
  __threadfence();   // acquire: invalidate stale cached rowsum/diag

  float l = 0.f, g = 0.f;
  #pragma unroll
  for (int i = 0; i < 8; ++i) {
    const int n = tid + i * 256;   // 0..2047
    const float se = rowsum[n];
    const float sk = rowsum[NB + n];
    const float d_ee  = diag[0 * NB + n];
    const float d_ek  = diag[1 * NB + n];
    const float d_eet = diag[2 * NB + n];
    const float d_ekt = diag[3 * NB + n];
    const float d_kk  = diag[5 * NB + n];
    const float d_ket = diag[6 * NB + n];
    const float d_kkt = diag[7 * NB + n];
    const float num_e = d_ek + d_eet + d_ekt;
    const float num_k = d_ek + d_ket + d_kkt;   // k.e diag == e.k diag (mirror)
    l += logf((se - d_ee) / num_e) + logf((sk - d_kk) / num_k);
    g += reg_partial[n];
  }
  #pragma unroll
  for (int o = 1; o < 64; o <<= 1) { l += __shfl_xor(l, o); g += __shfl_xor(g, o); }
  if (lane == 0) { redR[wave] = l; redR[8 + wave] = g; }
  __syncthreads();
  if (tid == 0) {
    const float L = redR[0] + redR[1] + redR[2] + redR[3];
    const float G = redR[8] + redR[9] + redR[10] + redR[11];
    const float contrastive = L * (1.0f / (2.0f * NB));
    const float cs = G * (1.0f / NB);
    out[0] = contrastive + LAMBDA_CS * cs;
    out[1] = contrastive;
    out[2] = cs;
  }
}

// ---------------------------------------------------------------------------
extern "C" void kernel_launch(void* const* d_in, const int* in_sizes, int n_in,
                              void* d_out, int out_size, void* d_ws, size_t ws_size,
                              hipStream_t stream) {
  const float* english = (const float*)d_in[0];
  const float* etok    = (const float*)d_in[1];
  const float* ktoe    = (const float*)d_in[2];
  const float* korean  = (const float*)d_in[3];
  const float* ratios  = (const float*)d_in[4];

  char* ws = (char*)d_ws;
  const size_t OFF_M    = 0;                                   // 16777216 B
  const size_t OFF_ROW  = OFF_M + (size_t)8192 * 1024 * 2;     // 4096*4
  const size_t OFF_DIAG = OFF_ROW + (size_t)4096 * 4;          // 8*2048*4
  const size_t OFF_REG  = OFF_DIAG + 8 * NB * sizeof(float);   // 2048*4
  const size_t OFF_CNT  = OFF_REG + NB * sizeof(float);        // 4

  ushort* M           = (ushort*)(ws + OFF_M);
  float* rowsum       = (float*)(ws + OFF_ROW);
  float* diag         = (float*)(ws + OFF_DIAG);
  float* reg_partial  = (float*)(ws + OFF_REG);
  int*   counter      = (int*)(ws + OFF_CNT);

  k_norm_reg<<<dim3(NB), 256, 0, stream>>>(english, korean, etok, ktoe, ratios,
                                           M, reg_partial, rowsum, counter);
  k_gemm_exp_rowsum<<<dim3(1552), 256, 0, stream>>>(M, rowsum, diag,
                                                    reg_partial, counter,
                                                    (float*)d_out);
}

// Round 9
// 170.756 us; speedup vs baseline: 1.5753x; 1.4608x over previous
//
#include <hip/hip_runtime.h>
#include <math.h>

// Problem constants
#define NB   2048     // batch
#define ND   1024     // dim
#define INV_TEMP 10.0f
#define LAMBDA_CS 0.5f

using short8  = __attribute__((ext_vector_type(8))) short;
using floatx4 = __attribute__((ext_vector_type(4))) float;

__device__ __forceinline__ ushort f32_to_bf16_rne(float f) {
  union { float f; unsigned u; } v; v.f = f;
  unsigned u = v.u;
  u += 0x7FFFu + ((u >> 16) & 1u);   // round-to-nearest-even
  return (ushort)(u >> 16);
}

// ---------------------------------------------------------------------------
// Kernel 1: fused row L2-normalize (-> bf16 M, t-order {e,k,et,kt}) + cs-reg
// partial per row + rowsum zero-init. One block per row b.
// ---------------------------------------------------------------------------
__global__ __launch_bounds__(256) void k_norm_reg(
    const float* __restrict__ e, const float* __restrict__ k,
    const float* __restrict__ et, const float* __restrict__ kt,
    const float* __restrict__ ratios,
    ushort* __restrict__ M, float* __restrict__ reg_partial,
    float* __restrict__ rowsum)
{
  const int b = blockIdx.x, tid = threadIdx.x;
  const int wave = tid >> 6, lane = tid & 63;

  float4 ve  = ((const float4*)(e  + (size_t)b * ND))[tid];
  float4 vk  = ((const float4*)(k  + (size_t)b * ND))[tid];
  float4 vet = ((const float4*)(et + (size_t)b * ND))[tid];
  float4 vkt = ((const float4*)(kt + (size_t)b * ND))[tid];

  float s0 = ve.x*ve.x + ve.y*ve.y + ve.z*ve.z + ve.w*ve.w;
  float s1 = vk.x*vk.x + vk.y*vk.y + vk.z*vk.z + vk.w*vk.w;
  float s2 = vet.x*vet.x + vet.y*vet.y + vet.z*vet.z + vet.w*vet.w;
  float s3 = vkt.x*vkt.x + vkt.y*vkt.y + vkt.z*vkt.z + vkt.w*vkt.w;
  #pragma unroll
  for (int o = 1; o < 64; o <<= 1) {
    s0 += __shfl_xor(s0, o); s1 += __shfl_xor(s1, o);
    s2 += __shfl_xor(s2, o); s3 += __shfl_xor(s3, o);
  }
  __shared__ float red[4][4];
  if (lane == 0) { red[wave][0] = s0; red[wave][1] = s1; red[wave][2] = s2; red[wave][3] = s3; }
  __syncthreads();
  const float ie  = 1.0f / sqrtf(red[0][0] + red[1][0] + red[2][0] + red[3][0]);
  const float ik  = 1.0f / sqrtf(red[0][1] + red[1][1] + red[2][1] + red[3][1]);
  const float iet = 1.0f / sqrtf(red[0][2] + red[1][2] + red[2][2] + red[3][2]);
  const float ikt = 1.0f / sqrtf(red[0][3] + red[1][3] + red[2][3] + red[3][3]);

  // write normalized bf16 rows, t order {0:e, 1:k, 2:et, 3:kt}
  {
    ushort o4[4];
    o4[0] = f32_to_bf16_rne(ve.x * ie);  o4[1] = f32_to_bf16_rne(ve.y * ie);
    o4[2] = f32_to_bf16_rne(ve.z * ie);  o4[3] = f32_to_bf16_rne(ve.w * ie);
    *(ushort4*)(M + ((size_t)0 * NB + b) * ND + tid * 4) = *(ushort4*)o4;
    o4[0] = f32_to_bf16_rne(vk.x * ik);  o4[1] = f32_to_bf16_rne(vk.y * ik);
    o4[2] = f32_to_bf16_rne(vk.z * ik);  o4[3] = f32_to_bf16_rne(vk.w * ik);
    *(ushort4*)(M + ((size_t)1 * NB + b) * ND + tid * 4) = *(ushort4*)o4;
    o4[0] = f32_to_bf16_rne(vet.x * iet); o4[1] = f32_to_bf16_rne(vet.y * iet);
    o4[2] = f32_to_bf16_rne(vet.z * iet); o4[3] = f32_to_bf16_rne(vet.w * iet);
    *(ushort4*)(M + ((size_t)2 * NB + b) * ND + tid * 4) = *(ushort4*)o4;
    o4[0] = f32_to_bf16_rne(vkt.x * ikt); o4[1] = f32_to_bf16_rne(vkt.y * ikt);
    o4[2] = f32_to_bf16_rne(vkt.z * ikt); o4[3] = f32_to_bf16_rne(vkt.w * ikt);
    *(ushort4*)(M + ((size_t)3 * NB + b) * ND + tid * 4) = *(ushort4*)o4;
  }

  // cs-reg partial
  const float r = ratios[b], rm = 1.0f - r;
  float a1 = 0.f, a2 = 0.f;
  {
    float en, kn, d1, d2;
    en = ve.x*ie; kn = vk.x*ik;
    d1 = vet.x*iet - (r*en + rm*kn); d2 = vkt.x*ikt - (rm*en + r*kn);
    a1 += d1*d1; a2 += d2*d2;
    en = ve.y*ie; kn = vk.y*ik;
    d1 = vet.y*iet - (r*en + rm*kn); d2 = vkt.y*ikt - (rm*en + r*kn);
    a1 += d1*d1; a2 += d2*d2;
    en = ve.z*ie; kn = vk.z*ik;
    d1 = vet.z*iet - (r*en + rm*kn); d2 = vkt.z*ikt - (rm*en + r*kn);
    a1 += d1*d1; a2 += d2*d2;
    en = ve.w*ie; kn = vk.w*ik;
    d1 = vet.w*iet - (r*en + rm*kn); d2 = vkt.w*ikt - (rm*en + r*kn);
    a1 += d1*d1; a2 += d2*d2;
  }
  #pragma unroll
  for (int o = 1; o < 64; o <<= 1) { a1 += __shfl_xor(a1, o); a2 += __shfl_xor(a2, o); }
  __shared__ float red2[4][2];
  if (lane == 0) { red2[wave][0] = a1; red2[wave][1] = a2; }
  __syncthreads();
  if (tid == 0) {
    float t1 = red2[0][0] + red2[1][0] + red2[2][0] + red2[3][0];
    float t2 = red2[0][1] + red2[1][1] + red2[2][1] + red2[3][1];
    reg_partial[b] = sqrtf(t1) + sqrtf(t2);
    rowsum[b] = 0.f;            // zero-init for gemm's atomics
    rowsum[NB + b] = 0.f;
  }
}

// ---------------------------------------------------------------------------
// Kernel 2: 128x128-tile, BK=32, 4-wave GEMM, DOUBLE-buffered with ONE
// __syncthreads per K-step (R0 had two). Unrolled x2 so LDS buffer indices
// are compile-time constants (alias analysis can prove the ds_reads don't
// touch the half being staged -> no spurious vmcnt(0) before reads, the
// R5 failure mode). Per step: barrier -> STAGE(t+1)->buf[1-p] ->
// COMPUTE(t) from buf[p]; the next barrier's vmcnt(0) guarantees stage
// completion; write-after-read is covered by the same barrier.
// Fused exp + atomic row-sum + PLAIN diag stores + symmetric col-sum
// mirror. NO fences / last-block reduction (R6: device-scope threadfence
// by 1552 blocks cost ~90 us).
//   Grid: 1552 = 1024 (right half) + 528 (upper-tri incl diagonal).
//   LDS 34 KB, VGPR+AGPR ~140 -> 3 blocks/CU (unchanged from R0).
// ---------------------------------------------------------------------------

#define GLDS(GP, LP)                                                           \
  __builtin_amdgcn_global_load_lds(                                            \
      (const __attribute__((address_space(1))) unsigned int*)(GP),             \
      (__attribute__((address_space(3))) unsigned int*)(LP), 16, 0, 0)

// stage K-tile TT (K-offset TT*32) into compile-time buffer BUF
#define STAGE(TT, BUF) do {                                                    \
  GLDS(gA + (size_t)(c0 * 16 + srow) * ND + (TT) * 32 + scol * 8,              \
       &As[BUF][c0 * 512]);                                                    \
  GLDS(gA + (size_t)(c1 * 16 + srow) * ND + (TT) * 32 + scol * 8,              \
       &As[BUF][c1 * 512]);                                                    \
  GLDS(gB + (size_t)(c0 * 16 + srow) * ND + (TT) * 32 + scol * 8,              \
       &Bs[BUF][c0 * 512]);                                                    \
  GLDS(gB + (size_t)(c1 * 16 + srow) * ND + (TT) * 32 + scol * 8,              \
       &Bs[BUF][c1 * 512]);                                                    \
} while (0)

#define COMPUTE(BUF) do {                                                      \
  short8 af_[4], bf_[4];                                                       \
  _Pragma("unroll")                                                            \
  for (int x = 0; x < 4; ++x) {                                                \
    af_[x] = *(const short8*)&As[BUF][aoff[x]];                                \
    bf_[x] = *(const short8*)&Bs[BUF][boff[x]];                                \
  }                                                                            \
  _Pragma("unroll")                                                            \
  for (int mi_ = 0; mi_ < 4; ++mi_)                                            \
    _Pragma("unroll")                                                          \
    for (int ni_ = 0; ni_ < 4; ++ni_)                                          \
      acc[mi_][ni_] = __builtin_amdgcn_mfma_f32_16x16x32_bf16(                 \
          af_[mi_], bf_[ni_], acc[mi_][ni_], 0, 0, 0);                         \
} while (0)

__global__ __launch_bounds__(256) void k_gemm_exp_rowsum(
    const ushort* __restrict__ M,
    float* __restrict__ rowsum,   // [4096] atomic accumulators
    float* __restrict__ diag)     // [2][4][2048] (side, t, n); slot 4 unused
{
  __shared__ __align__(16) ushort As[2][4096];   // 2 x 8KB
  __shared__ __align__(16) ushort Bs[2][4096];   // 2 x 8KB
  __shared__ float redR[256];
  __shared__ float redC[256];

  // decode (bx, by) from linear block id
  int bx, by;
  {
    int idx = blockIdx.x;
    if (idx < 1024) { by = idx >> 5; bx = 32 + (idx & 31); }
    else {
      int t = idx - 1024; by = 0;
      while (t >= 32 - by) { t -= 32 - by; ++by; }
      bx = by + t;
    }
  }
  const bool sym = (bx < 32) && (bx > by);
  const int j0 = bx * 128;
  const int i0 = by * 128;

  const int tid  = threadIdx.x;
  const int wave = tid >> 6;
  const int lane = tid & 63;
  const int q = lane >> 4;       // quad 0..3
  const int m = lane & 15;       // spatial index within 16
  const int wrow = (wave >> 1) * 64;
  const int wcol = (wave & 1) * 64;

  floatx4 acc[4][4] = {};

  // staging: chunk = 16 rows x 64B; XOR swizzle so ds_read_b128 is 2-way only
  const int srow = lane >> 2;
  const int scol = (lane & 3) ^ ((srow >> 1) & 3);
  const int c0 = wave * 2, c1 = c0 + 1;

  const ushort* gA = M + (size_t)i0 * ND;
  const ushort* gB = M + (size_t)j0 * ND;

  int aoff[4], boff[4];
  #pragma unroll
  for (int x = 0; x < 4; ++x) {
    const int sw = (q ^ ((m >> 1) & 3)) * 8;
    aoff[x] = (wrow + x * 16 + m) * 32 + sw;
    boff[x] = (wcol + x * 16 + m) * 32 + sw;
  }

  STAGE(0, 0);
  #pragma unroll 1
  for (int t = 0; t < 32; t += 2) {
    __syncthreads();              // buf0 staged (vmcnt0 drain); buf1 readers done
    STAGE(t + 1, 1);              // in flight under COMPUTE(0)
    COMPUTE(0);
    __syncthreads();              // buf1 staged; buf0 readers done
    if (t + 2 < 32) STAGE(t + 2, 0);
    COMPUTE(1);
  }

  // Epilogue. C/D layout: col = lane&15, row = q*4 + reg  [m89/m91]
  float colAcc[4] = {0.f, 0.f, 0.f, 0.f};
  #pragma unroll
  for (int mi = 0; mi < 4; ++mi) {
    #pragma unroll
    for (int r = 0; r < 4; ++r) {
      const int ig = i0 + wrow + mi * 16 + q * 4 + r;
      float s = 0.f;
      #pragma unroll
      for (int ni = 0; ni < 4; ++ni) {
        const float v = __expf(acc[mi][ni][r] * INV_TEMP);
        s += v;
        colAcc[ni] += v;
        const int jg = j0 + wcol + ni * 16 + m;
        if (((ig ^ jg) & (NB - 1)) == 0) {
          diag[(((ig >> 11) << 2) + (jg >> 11)) * NB + (ig & (NB - 1))] = v;
        }
      }
      s += __shfl_xor(s, 1);
      s += __shfl_xor(s, 2);
      s += __shfl_xor(s, 4);
      s += __shfl_xor(s, 8);
      if (m == 0) redR[(wave & 1) * 128 + wrow + mi * 16 + q * 4 + r] = s;
    }
  }
  #pragma unroll
  for (int ni = 0; ni < 4; ++ni) {
    float c = colAcc[ni];
    c += __shfl_xor(c, 16);
    c += __shfl_xor(c, 32);
    if (q == 0) redC[(wave >> 1) * 128 + wcol + ni * 16 + m] = c;
  }
  __syncthreads();
  if (tid < 128) {
    atomicAdd(&rowsum[i0 + tid], redR[tid] + redR[128 + tid]);
    if (sym)
      atomicAdd(&rowsum[j0 + tid], redC[tid] + redC[128 + tid]);
  }
}

// ---------------------------------------------------------------------------
// Kernel 3: per-row losses (rowsum direct; diag mirror for k.e) + final
// scalars. One 1024-thread block, 2 rows/thread; reads only ~88 KB.
// ---------------------------------------------------------------------------
__global__ __launch_bounds__(1024) void k_final(
    const float* __restrict__ rowsum, const float* __restrict__ diag,
    const float* __restrict__ reg_partial, float* __restrict__ out)
{
  const int tid = threadIdx.x;
  const int wave = tid >> 6, lane = tid & 63;
  float l = 0.f, g = 0.f;
  #pragma unroll
  for (int h = 0; h < 2; ++h) {
    const int n = tid + h * 1024;   // 0..2047
    const float se = rowsum[n];
    const float sk = rowsum[NB + n];
    const float d_ee  = diag[0 * NB + n];
    const float d_ek  = diag[1 * NB + n];
    const float d_eet = diag[2 * NB + n];
    const float d_ekt = diag[3 * NB + n];
    const float d_kk  = diag[5 * NB + n];
    const float d_ket = diag[6 * NB + n];
    const float d_kkt = diag[7 * NB + n];
    const float num_e = d_ek + d_eet + d_ekt;
    const float num_k = d_ek + d_ket + d_kkt;   // k.e diag == e.k diag (mirror)
    l += logf((se - d_ee) / num_e) + logf((sk - d_kk) / num_k);
    g += reg_partial[n];
  }
  #pragma unroll
  for (int o = 1; o < 64; o <<= 1) { l += __shfl_xor(l, o); g += __shfl_xor(g, o); }
  __shared__ float rl[16], rg[16];
  if (lane == 0) { rl[wave] = l; rg[wave] = g; }
  __syncthreads();
  if (tid == 0) {
    float L = 0.f, G = 0.f;
    #pragma unroll
    for (int i = 0; i < 16; ++i) { L += rl[i]; G += rg[i]; }
    const float contrastive = L * (1.0f / (2.0f * NB));
    const float cs = G * (1.0f / NB);
    out[0] = contrastive + LAMBDA_CS * cs;
    out[1] = contrastive;
    out[2] = cs;
  }
}

// ---------------------------------------------------------------------------
extern "C" void kernel_launch(void* const* d_in, const int* in_sizes, int n_in,
                              void* d_out, int out_size, void* d_ws, size_t ws_size,
                              hipStream_t stream) {
  const float* english = (const float*)d_in[0];
  const float* etok    = (const float*)d_in[1];
  const float* ktoe    = (const float*)d_in[2];
  const float* korean  = (const float*)d_in[3];
  const float* ratios  = (const float*)d_in[4];

  char* ws = (char*)d_ws;
  const size_t OFF_M    = 0;                                   // 16777216 B
  const size_t OFF_ROW  = OFF_M + (size_t)8192 * 1024 * 2;     // 4096*4
  const size_t OFF_DIAG = OFF_ROW + (size_t)4096 * 4;          // 8*2048*4
  const size_t OFF_REG  = OFF_DIAG + 8 * NB * sizeof(float);   // 2048*4

  ushort* M           = (ushort*)(ws + OFF_M);
  float* rowsum       = (float*)(ws + OFF_ROW);
  float* diag         = (float*)(ws + OFF_DIAG);
  float* reg_partial  = (float*)(ws + OFF_REG);

  k_norm_reg<<<dim3(NB), 256, 0, stream>>>(english, korean, etok, ktoe, ratios,
                                           M, reg_partial, rowsum);
  k_gemm_exp_rowsum<<<dim3(1552), 256, 0, stream>>>(M, rowsum, diag);
  k_final<<<dim3(1), 1024, 0, stream>>>(rowsum, diag, reg_partial, (float*)d_out);
}